// Round 4
// baseline (4252.965 us; speedup 1.0000x reference)
//
#include <hip/hip_runtime.h>
#include <math.h>

#define NTOK 16384
#define DIM 512
#define QLV 8
#define KCODE 1024
#define BM 64
#define BK 256
#define DC 32
#define NDC (DIM / DC)   // 16 d-chunks
#define NCK (KCODE / BK) // 4 code chunks
#define TAU 5e-4f

__global__ __launch_bounds__(256) void zero_ws(float* ws) {
  int i = blockIdx.x * 256 + threadIdx.x;
  // counts (Q*K) + commit (Q) + rescue counters (Q)
  for (int k = i; k < QLV * KCODE + 2 * QLV; k += gridDim.x * 256) ws[k] = 0.f;
}

// ---- numpy float32 replication helpers -------------------------------------
// np.sum over contiguous n=512 fp32: pairwise tree (P128+P128)+(P128+P128);
// each 128-block via the AVX512 SIMD path: 8 zmm accumulators combined
// ((r0+r1)+(r2+r3))+((r4+r5)+(r6+r7)) lanewise, then _mm512_reduce_add_ps tree.
__device__ __forceinline__ float np_blk128_sq(const float* __restrict__ x) {
#pragma clang fp contract(off)
  float L[16];
#pragma unroll
  for (int j = 0; j < 16; ++j) {
    const float a0 = x[j] * x[j];
    const float a1 = x[16 + j] * x[16 + j];
    const float a2 = x[32 + j] * x[32 + j];
    const float a3 = x[48 + j] * x[48 + j];
    const float a4 = x[64 + j] * x[64 + j];
    const float a5 = x[80 + j] * x[80 + j];
    const float a6 = x[96 + j] * x[96 + j];
    const float a7 = x[112 + j] * x[112 + j];
    L[j] = ((a0 + a1) + (a2 + a3)) + ((a4 + a5) + (a6 + a7));
  }
  float T3[8];
#pragma unroll
  for (int i = 0; i < 8; ++i) T3[i] = L[i] + L[i + 8];
  float T6[4];
#pragma unroll
  for (int j = 0; j < 4; ++j) T6[j] = T3[j] + T3[j + 4];
  return (T6[0] + T6[2]) + (T6[1] + T6[3]);
}

__device__ __forceinline__ float np_sum512_sq(const float* __restrict__ x) {
#pragma clang fp contract(off)
  const float p0 = np_blk128_sq(x);
  const float p1 = np_blk128_sq(x + 128);
  const float p2 = np_blk128_sq(x + 256);
  const float p3 = np_blk128_sq(x + 384);
  const float s01 = p0 + p1;
  const float s23 = p2 + p3;
  return s01 + s23;
}

// OpenBLAS sgemm model: sequential-k FMA chain, kc=384 panel split.
__device__ __forceinline__ float np_dist(float A, const float* __restrict__ r,
                                         const float* __restrict__ c, float cn) {
#pragma clang fp contract(off)
  float b1 = 0.f;
#pragma unroll 8
  for (int d = 0; d < 384; ++d) b1 = __builtin_fmaf(r[d], c[d], b1);
  float b2 = 0.f;
#pragma unroll 8
  for (int d = 384; d < 512; ++d) b2 = __builtin_fmaf(r[d], c[d], b2);
  const float B = b1 + b2;
  const float t1 = 2.0f * B;   // exact
  const float t2 = A - t1;     // fl32 @ magnitude ~512
  return t2 + cn;              // fl32
}
// ---------------------------------------------------------------------------

__global__ __launch_bounds__(256) void cnorm_np_kernel(const float* __restrict__ cb,
                                                       float* __restrict__ cn) {
  const int row = blockIdx.x * 256 + threadIdx.x;  // [0, Q*K)
  cn[row] = np_sum512_sq(cb + (size_t)row * DIM);
}

template <bool FIRST, bool LAST>
__global__ __launch_bounds__(256, 2) void level_kernel(
    const float* __restrict__ x, float* __restrict__ resid,
    const float* __restrict__ cb, const float* __restrict__ cnorm,
    float* __restrict__ out_idx, float* __restrict__ counts,
    float* __restrict__ commit, int* __restrict__ rcnt,
    int* __restrict__ rlist, int qlev) {
  __shared__ float Rs[DC][BM + 4];
  __shared__ float Cs[DC][BK + 4];
  __shared__ float4 red[BM][17];
  __shared__ int chosen[BM];

  const int tid = threadIdx.x;
  const int tx = tid & 15;  // code group: codes tx*16+g
  const int ty = tid >> 4;  // token group: tokens ty+16j
  const int blk = blockIdx.x;
  const float* rin = FIRST ? x : resid;

  float v1[4], v2[4];
  int i1[4], i2[4];
#pragma unroll
  for (int j = 0; j < 4; ++j) { v1[j] = v2[j] = 3.4e38f; i1[j] = i2[j] = KCODE; }

  for (int ck = 0; ck < NCK; ++ck) {
    float acc[4][16];
#pragma unroll
    for (int j = 0; j < 4; ++j)
#pragma unroll
      for (int g = 0; g < 16; ++g) acc[j][g] = 0.f;

    for (int dc = 0; dc < NDC; ++dc) {
      __syncthreads();
#pragma unroll
      for (int u = 0; u < 2; ++u) {
        const int f4 = tid + u * 256;
        const int tok = f4 >> 3, d4 = f4 & 7;
        const float4 v =
            *(const float4*)(rin + (size_t)(blk * BM + tok) * DIM + dc * DC + d4 * 4);
        Rs[d4 * 4 + 0][tok] = v.x;
        Rs[d4 * 4 + 1][tok] = v.y;
        Rs[d4 * 4 + 2][tok] = v.z;
        Rs[d4 * 4 + 3][tok] = v.w;
      }
#pragma unroll
      for (int u = 0; u < 8; ++u) {
        const int f4 = tid + u * 256;
        const int code = f4 >> 3, d4 = f4 & 7;
        const float4 v =
            *(const float4*)(cb + (size_t)(ck * BK + code) * DIM + dc * DC + d4 * 4);
        Cs[d4 * 4 + 0][code] = v.x;
        Cs[d4 * 4 + 1][code] = v.y;
        Cs[d4 * 4 + 2][code] = v.z;
        Cs[d4 * 4 + 3][code] = v.w;
      }
      __syncthreads();
#pragma unroll 4
      for (int d = 0; d < DC; ++d) {
        const float r0 = Rs[d][ty];
        const float r1 = Rs[d][16 + ty];
        const float r2 = Rs[d][32 + ty];
        const float r3 = Rs[d][48 + ty];
        const float4* cp = (const float4*)&Cs[d][tx * 16];
#pragma unroll
        for (int q4 = 0; q4 < 4; ++q4) {
          const float4 cv = cp[q4];
          acc[0][q4 * 4 + 0] = fmaf(r0, cv.x, acc[0][q4 * 4 + 0]);
          acc[0][q4 * 4 + 1] = fmaf(r0, cv.y, acc[0][q4 * 4 + 1]);
          acc[0][q4 * 4 + 2] = fmaf(r0, cv.z, acc[0][q4 * 4 + 2]);
          acc[0][q4 * 4 + 3] = fmaf(r0, cv.w, acc[0][q4 * 4 + 3]);
          acc[1][q4 * 4 + 0] = fmaf(r1, cv.x, acc[1][q4 * 4 + 0]);
          acc[1][q4 * 4 + 1] = fmaf(r1, cv.y, acc[1][q4 * 4 + 1]);
          acc[1][q4 * 4 + 2] = fmaf(r1, cv.z, acc[1][q4 * 4 + 2]);
          acc[1][q4 * 4 + 3] = fmaf(r1, cv.w, acc[1][q4 * 4 + 3]);
          acc[2][q4 * 4 + 0] = fmaf(r2, cv.x, acc[2][q4 * 4 + 0]);
          acc[2][q4 * 4 + 1] = fmaf(r2, cv.y, acc[2][q4 * 4 + 1]);
          acc[2][q4 * 4 + 2] = fmaf(r2, cv.z, acc[2][q4 * 4 + 2]);
          acc[2][q4 * 4 + 3] = fmaf(r2, cv.w, acc[2][q4 * 4 + 3]);
          acc[3][q4 * 4 + 0] = fmaf(r3, cv.x, acc[3][q4 * 4 + 0]);
          acc[3][q4 * 4 + 1] = fmaf(r3, cv.y, acc[3][q4 * 4 + 1]);
          acc[3][q4 * 4 + 2] = fmaf(r3, cv.z, acc[3][q4 * 4 + 2]);
          acc[3][q4 * 4 + 3] = fmaf(r3, cv.w, acc[3][q4 * 4 + 3]);
        }
      }
    }
#pragma unroll
    for (int g = 0; g < 16; ++g) {
      const int c = ck * BK + tx * 16 + g;
      const float cn = cnorm[c];
#pragma unroll
      for (int j = 0; j < 4; ++j) {
        const float dist = fmaf(-2.f, acc[j][g], cn);
        if (dist < v1[j] || (dist == v1[j] && c < i1[j])) {
          v2[j] = v1[j]; i2[j] = i1[j]; v1[j] = dist; i1[j] = c;
        } else if (dist < v2[j] || (dist == v2[j] && c < i2[j])) {
          v2[j] = dist; i2[j] = c;
        }
      }
    }
  }
  __syncthreads();
#pragma unroll
  for (int j = 0; j < 4; ++j)
    red[16 * j + ty][tx] = make_float4(v1[j], __int_as_float(i1[j]), v2[j], __int_as_float(i2[j]));
  __syncthreads();
  if (tid < BM) {
    float V1 = 3.4e38f, V2 = 3.4e38f;
    int I1 = KCODE, I2 = KCODE;
#pragma unroll
    for (int p = 0; p < 16; ++p) {
      const float4 e = red[tid][p];
      const float a = e.x; const int ia = __float_as_int(e.y);
      const float b = e.z; const int ib = __float_as_int(e.w);
      if (a < V1 || (a == V1 && ia < I1)) { V2 = V1; I2 = I1; V1 = a; I1 = ia; }
      else if (a < V2 || (a == V2 && ia < I2)) { V2 = a; I2 = ia; }
      if (b < V1 || (b == V1 && ib < I1)) { V2 = V1; I2 = I1; V1 = b; I1 = ib; }
      else if (b < V2 || (b == V2 && ib < I2)) { V2 = b; I2 = ib; }
    }
    if (V2 - V1 < TAU) {  // near-tie: np-fp32 replication decides
      const int pos = atomicAdd(rcnt, 1);
      rlist[pos] = blk * BM + tid;
      chosen[tid] = -1;
    } else {
      chosen[tid] = I1;
      out_idx[(size_t)(blk * BM + tid) * QLV + qlev] = (float)I1;
      atomicAdd(&counts[I1], 1.0f);
    }
  }
  __syncthreads();
  {  // residual update (fp32 chain, bit-equal to np's) — fast-path tokens only
    const int t = tid >> 2, part = tid & 3;
    const size_t tok = (size_t)(blk * BM + t);
    const int idx = chosen[t];
    float sq = 0.f;
    if (idx >= 0) {
      const float4* cp = (const float4*)(cb + (size_t)idx * DIM);
      const float4* rp = (const float4*)(rin + tok * DIM);
      const float4* xp = (const float4*)(x + tok * DIM);
      float4* op = (float4*)(resid + tok * DIM);
#pragma unroll 4
      for (int k2 = 0; k2 < 32; ++k2) {
        const int d4 = part + k2 * 4;
        const float4 r = rp[d4], c4 = cp[d4];
        float4 rn;
        rn.x = r.x - c4.x; rn.y = r.y - c4.y; rn.z = r.z - c4.z; rn.w = r.w - c4.w;
        sq += rn.x * rn.x + rn.y * rn.y + rn.z * rn.z + rn.w * rn.w;
        if (LAST) {
          const float4 xv = xp[d4];
          float4 qv;
          qv.x = xv.x - rn.x; qv.y = xv.y - rn.y; qv.z = xv.z - rn.z; qv.w = xv.w - rn.w;
          op[d4] = qv;
        } else {
          op[d4] = rn;
        }
      }
    }
#pragma unroll
    for (int off = 32; off; off >>= 1) sq += __shfl_down(sq, off);
    if ((tid & 63) == 0) atomicAdd(commit, sq);
  }
}

// Near-tie finalization replicating numpy-fp32 semantics exactly.
template <bool LAST>
__global__ __launch_bounds__(256) void rescue_np(
    const float* __restrict__ x, const float* __restrict__ rin,
    float* __restrict__ resid, const float* __restrict__ cbq,
    const float* __restrict__ cnq, float* __restrict__ out_idx,
    float* __restrict__ counts, float* __restrict__ commit,
    const int* __restrict__ rcnt, const int* __restrict__ rlist, int qlev) {
  __shared__ float rsh[DIM];
  __shared__ float sA;
  __shared__ float wv[4];
  __shared__ int wi[4];
  __shared__ int bestk_s;
  const int tid = threadIdx.x;
  const int n = rcnt[0];
  for (int it = blockIdx.x; it < n; it += gridDim.x) {
    const int t = rlist[it];
    rsh[tid] = rin[(size_t)t * DIM + tid];
    rsh[256 + tid] = rin[(size_t)t * DIM + 256 + tid];
    __syncthreads();
    if (tid == 0) sA = np_sum512_sq(rsh);
    __syncthreads();
    const float A = sA;
    float bv = 3.4e38f;
    int bi = KCODE;
    for (int kk = 0; kk < 4; ++kk) {
      const int k = tid * 4 + kk;  // ascending per thread -> first-occurrence ties
      const float d = np_dist(A, rsh, cbq + (size_t)k * DIM, cnq[k]);
      if (d < bv) { bv = d; bi = k; }
    }
#pragma unroll
    for (int off = 32; off; off >>= 1) {
      const float ov = __shfl_down(bv, off);
      const int oi = __shfl_down(bi, off);
      if (ov < bv || (ov == bv && oi < bi)) { bv = ov; bi = oi; }
    }
    if ((tid & 63) == 0) { wv[tid >> 6] = bv; wi[tid >> 6] = bi; }
    __syncthreads();
    if (tid == 0) {
      float V = wv[0]; int I = wi[0];
#pragma unroll
      for (int w = 1; w < 4; ++w)
        if (wv[w] < V || (wv[w] == V && wi[w] < I)) { V = wv[w]; I = wi[w]; }
      bestk_s = I;
      out_idx[(size_t)t * QLV + qlev] = (float)I;
      atomicAdd(&counts[I], 1.0f);
    }
    __syncthreads();
    const float* crow = cbq + (size_t)bestk_s * DIM;
    float sq;
    {  // fp32 chain update (bit-equal to np's residual = residual - quant)
      const int d0 = tid, d1 = tid + 256;
      const float rn0 = rsh[d0] - crow[d0];
      const float rn1 = rsh[d1] - crow[d1];
      sq = rn0 * rn0 + rn1 * rn1;
      if (LAST) {
        resid[(size_t)t * DIM + d0] = x[(size_t)t * DIM + d0] - rn0;
        resid[(size_t)t * DIM + d1] = x[(size_t)t * DIM + d1] - rn1;
      } else {
        resid[(size_t)t * DIM + d0] = rn0;
        resid[(size_t)t * DIM + d1] = rn1;
      }
    }
#pragma unroll
    for (int off = 32; off; off >>= 1) sq += __shfl_down(sq, off);
    if ((tid & 63) == 0) wv[tid >> 6] = sq;
    __syncthreads();
    if (tid == 0)
      atomicAdd(commit, wv[0] + wv[1] + wv[2] + wv[3]);
    __syncthreads();  // protect rsh/wv before next list item
  }
}

__global__ __launch_bounds__(256) void finalize_scalars(const float* __restrict__ counts,
                                                        const float* __restrict__ commit,
                                                        float* __restrict__ out2) {
  const int tid = threadIdx.x;
  __shared__ float sh[4];
  __shared__ float perp_acc;
  if (tid == 0) perp_acc = 0.f;
  __syncthreads();
  for (int q = 0; q < QLV; ++q) {
    float h = 0.f;
    for (int k = tid; k < KCODE; k += 256) {
      const float p = counts[q * KCODE + k] * (1.0f / (float)NTOK);
      h += p * logf(p + 1e-10f);
    }
#pragma unroll
    for (int off = 32; off; off >>= 1) h += __shfl_down(h, off);
    if ((tid & 63) == 0) sh[tid >> 6] = h;
    __syncthreads();
    if (tid == 0) {
      const float H = sh[0] + sh[1] + sh[2] + sh[3];
      perp_acc += expf(-H);
    }
    __syncthreads();
  }
  if (tid == 0) {
    float closs = 0.f;
    for (int q = 0; q < QLV; ++q) closs += commit[q];
    out2[0] = closs * (0.25f / ((float)NTOK * (float)DIM));
    out2[1] = perp_acc * (1.0f / (float)QLV);
  }
}

extern "C" void kernel_launch(void* const* d_in, const int* in_sizes, int n_in,
                              void* d_out, int out_size, void* d_ws, size_t ws_size,
                              hipStream_t stream) {
  const float* x = (const float*)d_in[0];
  const float* cb = (const float*)d_in[1];
  float* out = (float*)d_out;
  float* ws = (float*)d_ws;

  float* resid = out;                      // N*D, becomes quantized at last level
  float* oidx = out + (size_t)NTOK * DIM;  // N*Q indices (as float)
  float* scal = oidx + (size_t)NTOK * QLV; // [loss, perplexity]
  float* counts = ws;                      // Q*K
  float* commit = ws + QLV * KCODE;        // Q
  int* rcnt = (int*)(ws + QLV * KCODE + QLV);  // Q rescue counters
  float* cnorm = ws + QLV * KCODE + 512;   // Q*K (np-tree sums of squares)
  int* rlist = (int*)(ws + QLV * KCODE + 512 + QLV * KCODE);  // NTOK

  hipLaunchKernelGGL(zero_ws, dim3(32), dim3(256), 0, stream, ws);
  hipLaunchKernelGGL(cnorm_np_kernel, dim3((QLV * KCODE) / 256), dim3(256), 0, stream,
                     cb, cnorm);
  for (int q = 0; q < QLV; ++q) {
    const float* cbq = cb + (size_t)q * KCODE * DIM;
    const float* cnq = cnorm + q * KCODE;
    float* ctq = counts + q * KCODE;
    float* cmq = commit + q;
    int* rcq = rcnt + q;
    const float* rin = (q == 0) ? x : resid;
    if (q == 0)
      hipLaunchKernelGGL((level_kernel<true, false>), dim3(NTOK / BM), dim3(256), 0, stream,
                         x, resid, cbq, cnq, oidx, ctq, cmq, rcq, rlist, q);
    else if (q == QLV - 1)
      hipLaunchKernelGGL((level_kernel<false, true>), dim3(NTOK / BM), dim3(256), 0, stream,
                         x, resid, cbq, cnq, oidx, ctq, cmq, rcq, rlist, q);
    else
      hipLaunchKernelGGL((level_kernel<false, false>), dim3(NTOK / BM), dim3(256), 0, stream,
                         x, resid, cbq, cnq, oidx, ctq, cmq, rcq, rlist, q);
    if (q == QLV - 1)
      hipLaunchKernelGGL((rescue_np<true>), dim3(256), dim3(256), 0, stream,
                         x, rin, resid, cbq, cnq, oidx, ctq, cmq, rcq, rlist, q);
    else
      hipLaunchKernelGGL((rescue_np<false>), dim3(256), dim3(256), 0, stream,
                         x, rin, resid, cbq, cnq, oidx, ctq, cmq, rcq, rlist, q);
  }
  hipLaunchKernelGGL(finalize_scalars, dim3(1), dim3(256), 0, stream, counts, commit, scal);
}

// Round 6
// 2645.818 us; speedup vs baseline: 1.6074x; 1.6074x over previous
//
#include <hip/hip_runtime.h>
#include <math.h>

#define NTOK 16384
#define DIM 512
#define QLV 8
#define KCODE 1024
#define BM 64
#define DC 8
#define NCH (DIM / DC)  // 64 d-chunks
#define TAU 5e-4f

__global__ __launch_bounds__(256) void zero_ws(float* ws) {
  int i = blockIdx.x * 256 + threadIdx.x;
  // counts (Q*K) + commit (Q) + rescue counters (Q)
  for (int k = i; k < QLV * KCODE + 2 * QLV; k += gridDim.x * 256) ws[k] = 0.f;
}

// ---- numpy float32 replication helpers (PROVEN in round 4 — do not touch) --
__device__ __forceinline__ float np_blk128_sq(const float* __restrict__ x) {
#pragma clang fp contract(off)
  float L[16];
#pragma unroll
  for (int j = 0; j < 16; ++j) {
    const float a0 = x[j] * x[j];
    const float a1 = x[16 + j] * x[16 + j];
    const float a2 = x[32 + j] * x[32 + j];
    const float a3 = x[48 + j] * x[48 + j];
    const float a4 = x[64 + j] * x[64 + j];
    const float a5 = x[80 + j] * x[80 + j];
    const float a6 = x[96 + j] * x[96 + j];
    const float a7 = x[112 + j] * x[112 + j];
    L[j] = ((a0 + a1) + (a2 + a3)) + ((a4 + a5) + (a6 + a7));
  }
  float T3[8];
#pragma unroll
  for (int i = 0; i < 8; ++i) T3[i] = L[i] + L[i + 8];
  float T6[4];
#pragma unroll
  for (int j = 0; j < 4; ++j) T6[j] = T3[j] + T3[j + 4];
  return (T6[0] + T6[2]) + (T6[1] + T6[3]);
}

__device__ __forceinline__ float np_sum512_sq(const float* __restrict__ x) {
#pragma clang fp contract(off)
  const float p0 = np_blk128_sq(x);
  const float p1 = np_blk128_sq(x + 128);
  const float p2 = np_blk128_sq(x + 256);
  const float p3 = np_blk128_sq(x + 384);
  const float s01 = p0 + p1;
  const float s23 = p2 + p3;
  return s01 + s23;
}

__device__ __forceinline__ float np_dist(float A, const float* __restrict__ r,
                                         const float* __restrict__ c, float cn) {
#pragma clang fp contract(off)
  float b1 = 0.f;
#pragma unroll 8
  for (int d = 0; d < 384; ++d) b1 = __builtin_fmaf(r[d], c[d], b1);
  float b2 = 0.f;
#pragma unroll 8
  for (int d = 384; d < 512; ++d) b2 = __builtin_fmaf(r[d], c[d], b2);
  const float B = b1 + b2;
  const float t1 = 2.0f * B;
  const float t2 = A - t1;
  return t2 + cn;
}
// ---------------------------------------------------------------------------

__global__ __launch_bounds__(256) void cnorm_np_kernel(const float* __restrict__ cb,
                                                       float* __restrict__ cn) {
  const int row = blockIdx.x * 256 + threadIdx.x;  // [0, Q*K)
  cn[row] = np_sum512_sq(cb + (size_t)row * DIM);
}

// lexicographic (val, idx) less-than
__device__ __forceinline__ bool lt2(float a, int ia, float b, int ib) {
  return a < b || (a == b && ia < ib);
}

template <bool FIRST, bool LAST>
__global__ __launch_bounds__(512, 2) void level_kernel(
    const float* __restrict__ x, float* __restrict__ resid,
    const float* __restrict__ cb, const float* __restrict__ cnorm,
    float* __restrict__ out_idx, float* __restrict__ counts,
    float* __restrict__ commit, int* __restrict__ rcnt,
    int* __restrict__ rlist, int qlev) {
  __shared__ float Rs[DC][BM + 4];      // [8][68]   ~2.2 KB, d-major token tile
  __shared__ float Cs[DC][KCODE + 4];   // [8][1028] ~32.9 KB, d-major code tile
  __shared__ int chosen[BM];

  const int tid = threadIdx.x;
  const int lane = tid & 63;
  const int ty = tid >> 6;  // wave id 0..7 -> tokens ty*8 .. ty*8+7
  const int tx = lane;      // code group: codes q*256 + tx*4 + j  (q=0..3, j=0..3)
  const int blk = blockIdx.x;
  const float* rin = FIRST ? x : resid;

  float acc[8][16];
#pragma unroll
  for (int j = 0; j < 8; ++j)
#pragma unroll
    for (int g = 0; g < 16; ++g) acc[j][g] = 0.f;

  float4 pc[4];
  float4 pr;
  {  // prefetch chunk 0
#pragma unroll
    for (int u = 0; u < 4; ++u) {
      const int f4 = tid + u * 512;
      const int code = f4 >> 1, d4 = f4 & 1;
      pc[u] = *(const float4*)(cb + (size_t)code * DIM + d4 * 4);
    }
    if (tid < 128) {
      const int tok = tid >> 1, d4 = tid & 1;
      pr = *(const float4*)(rin + (size_t)(blk * BM + tok) * DIM + d4 * 4);
    }
  }

  for (int dc = 0; dc < NCH; ++dc) {
    __syncthreads();  // previous chunk's compute done; LDS reusable
#pragma unroll
    for (int u = 0; u < 4; ++u) {
      const int f4 = tid + u * 512;
      const int code = f4 >> 1, d4 = f4 & 1;
      Cs[d4 * 4 + 0][code] = pc[u].x;
      Cs[d4 * 4 + 1][code] = pc[u].y;
      Cs[d4 * 4 + 2][code] = pc[u].z;
      Cs[d4 * 4 + 3][code] = pc[u].w;
    }
    if (tid < 128) {
      const int tok = tid >> 1, d4 = tid & 1;
      Rs[d4 * 4 + 0][tok] = pr.x;
      Rs[d4 * 4 + 1][tok] = pr.y;
      Rs[d4 * 4 + 2][tok] = pr.z;
      Rs[d4 * 4 + 3][tok] = pr.w;
    }
    if (dc + 1 < NCH) {  // prefetch next chunk (lands during compute)
      const int doff = (dc + 1) * DC;
#pragma unroll
      for (int u = 0; u < 4; ++u) {
        const int f4 = tid + u * 512;
        const int code = f4 >> 1, d4 = f4 & 1;
        pc[u] = *(const float4*)(cb + (size_t)code * DIM + doff + d4 * 4);
      }
      if (tid < 128) {
        const int tok = tid >> 1, d4 = tid & 1;
        pr = *(const float4*)(rin + (size_t)(blk * BM + tok) * DIM + doff + d4 * 4);
      }
    }
    __syncthreads();
#pragma unroll
    for (int d = 0; d < DC; ++d) {
      const float4 ra = *(const float4*)&Rs[d][ty * 8];      // tokens ty*8..+3
      const float4 rb = *(const float4*)&Rs[d][ty * 8 + 4];  // tokens ty*8+4..+7
#pragma unroll
      for (int q = 0; q < 4; ++q) {
        const float4 cv = *(const float4*)&Cs[d][q * 256 + tx * 4];
        const float c0 = cv.x, c1 = cv.y, c2 = cv.z, c3 = cv.w;
        acc[0][q * 4 + 0] = fmaf(ra.x, c0, acc[0][q * 4 + 0]);
        acc[0][q * 4 + 1] = fmaf(ra.x, c1, acc[0][q * 4 + 1]);
        acc[0][q * 4 + 2] = fmaf(ra.x, c2, acc[0][q * 4 + 2]);
        acc[0][q * 4 + 3] = fmaf(ra.x, c3, acc[0][q * 4 + 3]);
        acc[1][q * 4 + 0] = fmaf(ra.y, c0, acc[1][q * 4 + 0]);
        acc[1][q * 4 + 1] = fmaf(ra.y, c1, acc[1][q * 4 + 1]);
        acc[1][q * 4 + 2] = fmaf(ra.y, c2, acc[1][q * 4 + 2]);
        acc[1][q * 4 + 3] = fmaf(ra.y, c3, acc[1][q * 4 + 3]);
        acc[2][q * 4 + 0] = fmaf(ra.z, c0, acc[2][q * 4 + 0]);
        acc[2][q * 4 + 1] = fmaf(ra.z, c1, acc[2][q * 4 + 1]);
        acc[2][q * 4 + 2] = fmaf(ra.z, c2, acc[2][q * 4 + 2]);
        acc[2][q * 4 + 3] = fmaf(ra.z, c3, acc[2][q * 4 + 3]);
        acc[3][q * 4 + 0] = fmaf(ra.w, c0, acc[3][q * 4 + 0]);
        acc[3][q * 4 + 1] = fmaf(ra.w, c1, acc[3][q * 4 + 1]);
        acc[3][q * 4 + 2] = fmaf(ra.w, c2, acc[3][q * 4 + 2]);
        acc[3][q * 4 + 3] = fmaf(ra.w, c3, acc[3][q * 4 + 3]);
        acc[4][q * 4 + 0] = fmaf(rb.x, c0, acc[4][q * 4 + 0]);
        acc[4][q * 4 + 1] = fmaf(rb.x, c1, acc[4][q * 4 + 1]);
        acc[4][q * 4 + 2] = fmaf(rb.x, c2, acc[4][q * 4 + 2]);
        acc[4][q * 4 + 3] = fmaf(rb.x, c3, acc[4][q * 4 + 3]);
        acc[5][q * 4 + 0] = fmaf(rb.y, c0, acc[5][q * 4 + 0]);
        acc[5][q * 4 + 1] = fmaf(rb.y, c1, acc[5][q * 4 + 1]);
        acc[5][q * 4 + 2] = fmaf(rb.y, c2, acc[5][q * 4 + 2]);
        acc[5][q * 4 + 3] = fmaf(rb.y, c3, acc[5][q * 4 + 3]);
        acc[6][q * 4 + 0] = fmaf(rb.z, c0, acc[6][q * 4 + 0]);
        acc[6][q * 4 + 1] = fmaf(rb.z, c1, acc[6][q * 4 + 1]);
        acc[6][q * 4 + 2] = fmaf(rb.z, c2, acc[6][q * 4 + 2]);
        acc[6][q * 4 + 3] = fmaf(rb.z, c3, acc[6][q * 4 + 3]);
        acc[7][q * 4 + 0] = fmaf(rb.w, c0, acc[7][q * 4 + 0]);
        acc[7][q * 4 + 1] = fmaf(rb.w, c1, acc[7][q * 4 + 1]);
        acc[7][q * 4 + 2] = fmaf(rb.w, c2, acc[7][q * 4 + 2]);
        acc[7][q * 4 + 3] = fmaf(rb.w, c3, acc[7][q * 4 + 3]);
      }
    }
  }

  // fold: per thread top-2 over its 16 codes, per token
  float v1[8], v2[8];
  int i1[8], i2[8];
#pragma unroll
  for (int j = 0; j < 8; ++j) { v1[j] = v2[j] = 3.4e38f; i1[j] = i2[j] = KCODE; }
#pragma unroll
  for (int g = 0; g < 16; ++g) {
    const int c = (g >> 2) * 256 + tx * 4 + (g & 3);
    const float cn = cnorm[c];
#pragma unroll
    for (int j = 0; j < 8; ++j) {
      const float dist = fmaf(-2.f, acc[j][g], cn);
      if (lt2(dist, c, v1[j], i1[j])) {
        v2[j] = v1[j]; i2[j] = i1[j]; v1[j] = dist; i1[j] = c;
      } else if (lt2(dist, c, v2[j], i2[j])) {
        v2[j] = dist; i2[j] = c;
      }
    }
  }
  // intra-wave xor-butterfly top-2 merge (all 64 lanes = all 1024 codes)
#pragma unroll
  for (int off = 1; off < 64; off <<= 1) {
#pragma unroll
    for (int j = 0; j < 8; ++j) {
      const float w1 = __shfl_xor(v1[j], off);
      const int j1 = __shfl_xor(i1[j], off);
      const float w2 = __shfl_xor(v2[j], off);
      const int j2 = __shfl_xor(i2[j], off);
      if (lt2(w1, j1, v1[j], i1[j])) {
        // new best = (w1,j1); second = min((v1,i1),(w2,j2))
        if (lt2(v1[j], i1[j], w2, j2)) { v2[j] = v1[j]; i2[j] = i1[j]; }
        else { v2[j] = w2; i2[j] = j2; }
        v1[j] = w1; i1[j] = j1;
      } else {
        // best stays; second = min((v2,i2),(w1,j1))
        if (lt2(w1, j1, v2[j], i2[j])) { v2[j] = w1; i2[j] = j1; }
      }
    }
  }
  if (lane < 8) {
    const int tb = ty * 8 + lane;
    const float V1 = v1[lane], V2 = v2[lane];
    const int I1 = i1[lane];
    if (V2 - V1 < TAU) {  // near-tie: np-fp32 rescue decides
      const int pos = atomicAdd(rcnt, 1);
      rlist[pos] = blk * BM + tb;
      chosen[tb] = -1;
    } else {
      chosen[tb] = I1;
      out_idx[(size_t)(blk * BM + tb) * QLV + qlev] = (float)I1;
      atomicAdd(&counts[I1], 1.0f);
    }
  }
  __syncthreads();
  {  // residual update (fp32 chain, bit-equal to np's) — fast-path tokens only
    const int tb = tid >> 3, part = tid & 7;  // 8 threads per token
    const size_t tok = (size_t)(blk * BM + tb);
    const int idx = chosen[tb];
    float sq = 0.f;
    if (idx >= 0) {
      const float4* cp = (const float4*)(cb + (size_t)idx * DIM);
      const float4* rp = (const float4*)(rin + tok * DIM);
      const float4* xp = (const float4*)(x + tok * DIM);
      float4* op = (float4*)(resid + tok * DIM);
#pragma unroll 4
      for (int kk = 0; kk < 16; ++kk) {
        const int d4 = part + kk * 8;
        const float4 r = rp[d4], c4 = cp[d4];
        float4 rn;
        rn.x = r.x - c4.x; rn.y = r.y - c4.y; rn.z = r.z - c4.z; rn.w = r.w - c4.w;
        sq += rn.x * rn.x + rn.y * rn.y + rn.z * rn.z + rn.w * rn.w;
        if (LAST) {
          const float4 xv = xp[d4];
          float4 qv;
          qv.x = xv.x - rn.x; qv.y = xv.y - rn.y; qv.z = xv.z - rn.z; qv.w = xv.w - rn.w;
          op[d4] = qv;  // quantized = x - residual_new
        } else {
          op[d4] = rn;
        }
      }
    }
#pragma unroll
    for (int off = 32; off; off >>= 1) sq += __shfl_down(sq, off);
    if (lane == 0) atomicAdd(commit, sq);
  }
}

// Near-tie finalization replicating numpy-fp32 semantics exactly (PROVEN r4).
template <bool LAST>
__global__ __launch_bounds__(256) void rescue_np(
    const float* __restrict__ x, const float* __restrict__ rin,
    float* __restrict__ resid, const float* __restrict__ cbq,
    const float* __restrict__ cnq, float* __restrict__ out_idx,
    float* __restrict__ counts, float* __restrict__ commit,
    const int* __restrict__ rcnt, const int* __restrict__ rlist, int qlev) {
  __shared__ float rsh[DIM];
  __shared__ float sA;
  __shared__ float wv[4];
  __shared__ int wi[4];
  __shared__ int bestk_s;
  const int tid = threadIdx.x;
  const int n = rcnt[0];
  for (int it = blockIdx.x; it < n; it += gridDim.x) {
    const int t = rlist[it];
    rsh[tid] = rin[(size_t)t * DIM + tid];
    rsh[256 + tid] = rin[(size_t)t * DIM + 256 + tid];
    __syncthreads();
    if (tid == 0) sA = np_sum512_sq(rsh);
    __syncthreads();
    const float A = sA;
    float bv = 3.4e38f;
    int bi = KCODE;
    for (int kk = 0; kk < 4; ++kk) {
      const int k = tid * 4 + kk;  // ascending per thread -> first-occurrence ties
      const float d = np_dist(A, rsh, cbq + (size_t)k * DIM, cnq[k]);
      if (d < bv) { bv = d; bi = k; }
    }
#pragma unroll
    for (int off = 32; off; off >>= 1) {
      const float ov = __shfl_down(bv, off);
      const int oi = __shfl_down(bi, off);
      if (ov < bv || (ov == bv && oi < bi)) { bv = ov; bi = oi; }
    }
    if ((tid & 63) == 0) { wv[tid >> 6] = bv; wi[tid >> 6] = bi; }
    __syncthreads();
    if (tid == 0) {
      float V = wv[0]; int I = wi[0];
#pragma unroll
      for (int w = 1; w < 4; ++w)
        if (wv[w] < V || (wv[w] == V && wi[w] < I)) { V = wv[w]; I = wi[w]; }
      bestk_s = I;
      out_idx[(size_t)t * QLV + qlev] = (float)I;
      atomicAdd(&counts[I], 1.0f);
    }
    __syncthreads();
    const float* crow = cbq + (size_t)bestk_s * DIM;
    float sq;
    {
      const int d0 = tid, d1 = tid + 256;
      const float rn0 = rsh[d0] - crow[d0];
      const float rn1 = rsh[d1] - crow[d1];
      sq = rn0 * rn0 + rn1 * rn1;
      if (LAST) {
        resid[(size_t)t * DIM + d0] = x[(size_t)t * DIM + d0] - rn0;
        resid[(size_t)t * DIM + d1] = x[(size_t)t * DIM + d1] - rn1;
      } else {
        resid[(size_t)t * DIM + d0] = rn0;
        resid[(size_t)t * DIM + d1] = rn1;
      }
    }
#pragma unroll
    for (int off = 32; off; off >>= 1) sq += __shfl_down(sq, off);
    if ((tid & 63) == 0) wv[tid >> 6] = sq;
    __syncthreads();
    if (tid == 0)
      atomicAdd(commit, wv[0] + wv[1] + wv[2] + wv[3]);
    __syncthreads();  // protect rsh/wv before next list item
  }
}

__global__ __launch_bounds__(256) void finalize_scalars(const float* __restrict__ counts,
                                                        const float* __restrict__ commit,
                                                        float* __restrict__ out2) {
  const int tid = threadIdx.x;
  __shared__ float sh[4];
  __shared__ float perp_acc;
  if (tid == 0) perp_acc = 0.f;
  __syncthreads();
  for (int q = 0; q < QLV; ++q) {
    float h = 0.f;
    for (int k = tid; k < KCODE; k += 256) {
      const float p = counts[q * KCODE + k] * (1.0f / (float)NTOK);
      h += p * logf(p + 1e-10f);
    }
#pragma unroll
    for (int off = 32; off; off >>= 1) h += __shfl_down(h, off);
    if ((tid & 63) == 0) sh[tid >> 6] = h;
    __syncthreads();
    if (tid == 0) {
      const float H = sh[0] + sh[1] + sh[2] + sh[3];
      perp_acc += expf(-H);
    }
    __syncthreads();
  }
  if (tid == 0) {
    float closs = 0.f;
    for (int q = 0; q < QLV; ++q) closs += commit[q];
    out2[0] = closs * (0.25f / ((float)NTOK * (float)DIM));
    out2[1] = perp_acc * (1.0f / (float)QLV);
  }
}

extern "C" void kernel_launch(void* const* d_in, const int* in_sizes, int n_in,
                              void* d_out, int out_size, void* d_ws, size_t ws_size,
                              hipStream_t stream) {
  const float* x = (const float*)d_in[0];
  const float* cb = (const float*)d_in[1];
  float* out = (float*)d_out;
  float* ws = (float*)d_ws;

  float* resid = out;                      // N*D, becomes quantized at last level
  float* oidx = out + (size_t)NTOK * DIM;  // N*Q indices (as float)
  float* scal = oidx + (size_t)NTOK * QLV; // [loss, perplexity]
  float* counts = ws;                      // Q*K
  float* commit = ws + QLV * KCODE;        // Q
  int* rcnt = (int*)(ws + QLV * KCODE + QLV);  // Q rescue counters
  float* cnorm = ws + QLV * KCODE + 512;   // Q*K (np-tree sums of squares)
  int* rlist = (int*)(ws + QLV * KCODE + 512 + QLV * KCODE);  // NTOK

  hipLaunchKernelGGL(zero_ws, dim3(32), dim3(256), 0, stream, ws);
  hipLaunchKernelGGL(cnorm_np_kernel, dim3((QLV * KCODE) / 256), dim3(256), 0, stream,
                     cb, cnorm);
  for (int q = 0; q < QLV; ++q) {
    const float* cbq = cb + (size_t)q * KCODE * DIM;
    const float* cnq = cnorm + q * KCODE;
    float* ctq = counts + q * KCODE;
    float* cmq = commit + q;
    int* rcq = rcnt + q;
    const float* rin = (q == 0) ? x : resid;
    if (q == 0)
      hipLaunchKernelGGL((level_kernel<true, false>), dim3(NTOK / BM), dim3(512), 0, stream,
                         x, resid, cbq, cnq, oidx, ctq, cmq, rcq, rlist, q);
    else if (q == QLV - 1)
      hipLaunchKernelGGL((level_kernel<false, true>), dim3(NTOK / BM), dim3(512), 0, stream,
                         x, resid, cbq, cnq, oidx, ctq, cmq, rcq, rlist, q);
    else
      hipLaunchKernelGGL((level_kernel<false, false>), dim3(NTOK / BM), dim3(512), 0, stream,
                         x, resid, cbq, cnq, oidx, ctq, cmq, rcq, rlist, q);
    if (q == QLV - 1)
      hipLaunchKernelGGL((rescue_np<true>), dim3(256), dim3(256), 0, stream,
                         x, rin, resid, cbq, cnq, oidx, ctq, cmq, rcq, rlist, q);
    else
      hipLaunchKernelGGL((rescue_np<false>), dim3(256), dim3(256), 0, stream,
                         x, rin, resid, cbq, cnq, oidx, ctq, cmq, rcq, rlist, q);
  }
  hipLaunchKernelGGL(finalize_scalars, dim3(1), dim3(256), 0, stream, counts, commit, scal);
}